// Round 4
// baseline (1534.991 us; speedup 1.0000x reference)
//
#include <hip/hip_runtime.h>

// ---------------------------------------------------------------------------
// net_39041252721195: SplineConv(1->2) + ELU + BN + SplineConv(2->4) + BN
//                     + 4x4 grid max-pool + FC(64->4)
// K=2, DIM=3: pseudo in [0,1) => lo==0, idx==b. Basis weights = trilinear.
//
// Round 4: LDS fp atomics measured at ~10-17 cyc/LANE (serialized) -> they
// were the floor of rounds 2-3. Replace aggregation with node-exact counting
// sort (records -> registers -> LDS-sorted by node) + pure register
// accumulation (thread-pair per node). Zero fp atomics per edge; 4 int LDS
// atomics/edge total across the pipeline.
// ---------------------------------------------------------------------------

#define TPB 256
#define NODES_PER_BUCK 128
#define BUCK_SHIFT 7
#define NBUCK 2048                  // N / 128 (N = 262144)
#define BPART 512                   // partition blocks
#define CAP 2432                    // bucket record capacity (mean 2048, sd 45; 8.5 sigma)

__device__ __forceinline__ void basis_weights(float f0, float f1, float f2, float w[8]) {
    float g0 = 1.f - f0, g1 = 1.f - f1, g2 = 1.f - f2;
    w[0] = g0 * g1 * g2;  w[1] = f0 * g1 * g2;
    w[2] = g0 * f1 * g2;  w[3] = f0 * f1 * g2;
    w[4] = g0 * g1 * f2;  w[5] = f0 * g1 * f2;
    w[6] = g0 * f1 * f2;  w[7] = f0 * f1 * f2;
}

// ---- pass 1: per-block LDS histogram of dst>>7 -----------------------------
__global__ void hist_kernel(const int* __restrict__ ei, int E,
                            unsigned* __restrict__ cntArr /* [NBUCK][BPART] */) {
    __shared__ unsigned h[NBUCK];
    for (int i = threadIdx.x; i < NBUCK; i += TPB) h[i] = 0u;
    __syncthreads();
    int ch = (E + BPART - 1) / BPART;
    int s = blockIdx.x * ch;
    int e_end = min(E, s + ch);
    int e = s + threadIdx.x * 4;
    for (; e + 4 <= e_end; e += TPB * 4) {
        int4 d4 = *(const int4*)&ei[E + e];
        atomicAdd(&h[d4.x >> BUCK_SHIFT], 1u);
        atomicAdd(&h[d4.y >> BUCK_SHIFT], 1u);
        atomicAdd(&h[d4.z >> BUCK_SHIFT], 1u);
        atomicAdd(&h[d4.w >> BUCK_SHIFT], 1u);
    }
    for (e = e_end - (e_end - s) % (TPB * 4) + threadIdx.x; e < e_end; e += TPB)
        atomicAdd(&h[ei[E + e] >> BUCK_SHIFT], 1u);
    __syncthreads();
    for (int i = threadIdx.x; i < NBUCK; i += TPB)
        cntArr[i * BPART + blockIdx.x] = h[i];
}

// ---- scan: per-bucket exclusive prefix over BPART values, IN PLACE ---------
__global__ void scan512_kernel(unsigned* __restrict__ data,
                               unsigned* __restrict__ totals) {
    __shared__ unsigned s[BPART];
    int t = threadIdx.x, g = blockIdx.x;
    unsigned v = data[g * BPART + t];
    s[t] = v;
    __syncthreads();
    for (int o = 1; o < BPART; o <<= 1) {
        unsigned u = (t >= o) ? s[t - o] : 0u;
        __syncthreads();
        s[t] += u;
        __syncthreads();
    }
    data[g * BPART + t] = s[t] - v;     // exclusive
    if (t == BPART - 1) totals[g] = s[t];
}

// ---- scan of NBUCK bucket totals -> bucket bases; set nodeStart[N]=E -------
__global__ void scanbase_kernel(const unsigned* __restrict__ in,   // [NBUCK]
                                unsigned* __restrict__ excl,       // [NBUCK]
                                unsigned* __restrict__ nodeStart,
                                int N, unsigned Etot) {
    __shared__ unsigned s[512];
    int t = threadIdx.x;
    unsigned v0 = in[4 * t], v1 = in[4 * t + 1], v2 = in[4 * t + 2], v3 = in[4 * t + 3];
    unsigned sum = v0 + v1 + v2 + v3;
    s[t] = sum;
    __syncthreads();
    for (int o = 1; o < 512; o <<= 1) {
        unsigned u = (t >= o) ? s[t - o] : 0u;
        __syncthreads();
        s[t] += u;
        __syncthreads();
    }
    unsigned run = s[t] - sum;
    excl[4 * t] = run;          run += v0;
    excl[4 * t + 1] = run;      run += v1;
    excl[4 * t + 2] = run;      run += v2;
    excl[4 * t + 3] = run;
    if (t == 0) nodeStart[N] = Etot;
}

// ---- scatter edges into bucket-contiguous 16B records ----------------------
__global__ void scatter_kernel(const int* __restrict__ ei,
                               const float* __restrict__ attr,
                               const unsigned* __restrict__ bktBase,
                               const unsigned* __restrict__ preArr,
                               uint4* __restrict__ part, int E) {
    __shared__ unsigned cursor[NBUCK];
    for (int i = threadIdx.x; i < NBUCK; i += TPB)
        cursor[i] = bktBase[i] + preArr[i * BPART + blockIdx.x];
    __syncthreads();
    int ch = (E + BPART - 1) / BPART;
    int s = blockIdx.x * ch;
    int e_end = min(E, s + ch);
    int e = s + threadIdx.x * 4;
    for (; e + 4 <= e_end; e += TPB * 4) {
        int4 s4 = *(const int4*)&ei[e];
        int4 d4 = *(const int4*)&ei[E + e];
        float4 a0 = *(const float4*)&attr[3 * e];
        float4 a1 = *(const float4*)&attr[3 * e + 4];
        float4 a2 = *(const float4*)&attr[3 * e + 8];
        int srcs[4] = {s4.x, s4.y, s4.z, s4.w};
        int dsts[4] = {d4.x, d4.y, d4.z, d4.w};
        float f[4][3] = {{a0.x, a0.y, a0.z}, {a0.w, a1.x, a1.y},
                         {a1.z, a1.w, a2.x}, {a2.y, a2.z, a2.w}};
#pragma unroll
        for (int j = 0; j < 4; j++) {
            unsigned pos = atomicAdd(&cursor[dsts[j] >> BUCK_SHIFT], 1u);
            uint4 r;
            r.x = (unsigned)srcs[j] | ((unsigned)(dsts[j] & (NODES_PER_BUCK - 1)) << 18);
            r.y = __float_as_uint(f[j][0]);
            r.z = __float_as_uint(f[j][1]);
            r.w = __float_as_uint(f[j][2]);
            part[pos] = r;
        }
    }
    for (e = e_end - (e_end - s) % (TPB * 4) + threadIdx.x; e < e_end; e += TPB) {
        int src = ei[e], dst = ei[E + e];
        unsigned pos = atomicAdd(&cursor[dst >> BUCK_SHIFT], 1u);
        uint4 r;
        r.x = (unsigned)src | ((unsigned)(dst & (NODES_PER_BUCK - 1)) << 18);
        r.y = __float_as_uint(attr[3 * e]);
        r.z = __float_as_uint(attr[3 * e + 1]);
        r.w = __float_as_uint(attr[3 * e + 2]);
        part[pos] = r;
    }
}

// ---- sort bucket by node (in place) + layer-1 register aggregation ---------
// ELU + mean + BN1-stats fused; writes nodeStart for agg2.
__global__ void sortagg1_kernel(uint4* __restrict__ part,
                                const unsigned* __restrict__ bktBase,
                                const unsigned* __restrict__ bktTot,
                                const float* __restrict__ x,
                                const float* __restrict__ W1,
                                float* __restrict__ h1,
                                unsigned* __restrict__ nodeStart,
                                float* __restrict__ accum /* sum[2], sq[2] */) {
    __shared__ unsigned hist[NODES_PER_BUCK];
    __shared__ unsigned cursor[NODES_PER_BUCK];
    __shared__ uint4 sRec[CAP];
    int tid = threadIdx.x;
    if (tid < NODES_PER_BUCK) hist[tid] = 0u;
    float w1[16];
#pragma unroll
    for (int i = 0; i < 16; i++) w1[i] = W1[i];
    __syncthreads();
    int g = blockIdx.x;
    unsigned s = bktBase[g], n_e = bktTot[g];
    uint4 rec[10];
#pragma unroll
    for (int j = 0; j < 10; j++) {
        unsigned i = (unsigned)tid + j * 256u;
        if (i < n_e) {
            rec[j] = part[s + i];
            atomicAdd(&hist[rec[j].x >> 18], 1u);   // 1 int atomic/edge
        }
    }
    __syncthreads();
    // exclusive scan of hist[128] (Hillis-Steele, all threads hit barriers)
    unsigned myc = (tid < NODES_PER_BUCK) ? hist[tid] : 0u;
    for (int o = 1; o < NODES_PER_BUCK; o <<= 1) {
        unsigned u = 0u;
        if (tid < NODES_PER_BUCK && tid >= o) u = hist[tid - o];
        __syncthreads();
        if (tid < NODES_PER_BUCK) hist[tid] += u;
        __syncthreads();
    }
    if (tid < NODES_PER_BUCK) {
        unsigned excl = hist[tid] - myc;
        cursor[tid] = excl;
        nodeStart[(g << BUCK_SHIFT) + tid] = s + excl;
    }
    __syncthreads();
#pragma unroll
    for (int j = 0; j < 10; j++) {
        unsigned i = (unsigned)tid + j * 256u;
        if (i < n_e) {
            unsigned slot = atomicAdd(&cursor[rec[j].x >> 18], 1u);  // 1 int atomic/edge
            sRec[slot] = rec[j];
        }
    }
    __syncthreads();
    // register aggregation: thread pair (2t,2t+1) -> node t
    int t2 = tid >> 1, half = tid & 1;
    unsigned end = cursor[t2];                       // == inclusive after pass B
    unsigned st  = (t2 == 0) ? 0u : cursor[t2 - 1];
    float a0 = 0.f, a1 = 0.f;
    for (unsigned i = st + half; i < end; i += 2) {
        uint4 r = sRec[i];
        int src = r.x & 0x3FFFF;
        float f0 = __uint_as_float(r.y), f1 = __uint_as_float(r.z), f2 = __uint_as_float(r.w);
        float w[8];
        basis_weights(f0, f1, f2, w);
        float wv0 = 0.f, wv1 = 0.f;
#pragma unroll
        for (int b = 0; b < 8; b++) {
            wv0 += w[b] * w1[2 * b];
            wv1 += w[b] * w1[2 * b + 1];
        }
        float xs = x[src];
        a0 += xs * wv0;
        a1 += xs * wv1;
    }
    a0 += __shfl_xor(a0, 1, 64);
    a1 += __shfl_xor(a1, 1, 64);
    float deg = (float)(end - st);
    float cm = deg > 1.f ? deg : 1.f;
    float a = a0 / cm, b = a1 / cm;
    a = a > 0.f ? a : (__expf(a) - 1.f);
    b = b > 0.f ? b : (__expf(b) - 1.f);
    int n = (g << BUCK_SHIFT) + t2;
    if (half == 0) { h1[2 * n] = a; h1[2 * n + 1] = b; }
    // write node-sorted records back in place (coalesced)
    for (unsigned i = tid; i < n_e; i += 256u) part[s + i] = sRec[i];
    // BN1 stats (even lanes contribute)
    float ts0 = half ? 0.f : a, ts1 = half ? 0.f : b;
    float tq0 = half ? 0.f : a * a, tq1 = half ? 0.f : b * b;
#pragma unroll
    for (int o = 32; o > 0; o >>= 1) {
        ts0 += __shfl_down(ts0, o, 64);
        ts1 += __shfl_down(ts1, o, 64);
        tq0 += __shfl_down(tq0, o, 64);
        tq1 += __shfl_down(tq1, o, 64);
    }
    if ((tid & 63) == 0) {
        atomicAdd(&accum[0], ts0);
        atomicAdd(&accum[1], ts1);
        atomicAdd(&accum[2], tq0);
        atomicAdd(&accum[3], tq1);
    }
}

// ---- BN params: scale = gamma*rsqrt(var+eps); shift = beta - mu*scale ------
__global__ void bnparams_kernel(const float* __restrict__ accum,
                                const float* __restrict__ gamma,
                                const float* __restrict__ beta,
                                float* __restrict__ params, int C, float invN) {
    int c = threadIdx.x;
    if (c < C) {
        float mu  = accum[c] * invN;
        float var = accum[C + c] * invN - mu * mu;
        float sc  = gamma[c] * rsqrtf(var + 1e-5f);
        params[c] = sc;
        params[C + c] = beta[c] - mu * sc;
    }
}

// ---- layer 2: atomic-free register aggregation over sorted runs ------------
__global__ void agg2_kernel(const uint4* __restrict__ part,      // node-sorted
                            const unsigned* __restrict__ nodeStart,
                            const float* __restrict__ h1,
                            const float* __restrict__ W2,        // [8][2][4]
                            const float* __restrict__ params,    // sc1[2], sh1[2]
                            float* __restrict__ h2,
                            float* __restrict__ accum /* sum[4], sq[4] */) {
    float w2[64];
#pragma unroll
    for (int i = 0; i < 64; i++) w2[i] = W2[i];
    float sc0 = params[0], sc1 = params[1], sh0 = params[2], sh1 = params[3];
    int tid = threadIdx.x;
    int t2 = tid >> 1, half = tid & 1;
    int n = (blockIdx.x << BUCK_SHIFT) + t2;
    unsigned st = nodeStart[n], end = nodeStart[n + 1];
    float m0 = 0.f, m1 = 0.f, m2 = 0.f, m3 = 0.f;
    for (unsigned i = st + half; i < end; i += 2) {
        uint4 r = part[i];
        int src = r.x & 0x3FFFF;
        float f0 = __uint_as_float(r.y), f1 = __uint_as_float(r.z), f2 = __uint_as_float(r.w);
        float w[8];
        basis_weights(f0, f1, f2, w);
        float2 hv = *(const float2*)&h1[2 * src];
        float a = hv.x * sc0 + sh0;
        float b = hv.y * sc1 + sh1;
#pragma unroll
        for (int bb = 0; bb < 8; bb++) {
            float wb = w[bb];
            const float* Wb = &w2[8 * bb];
            float wa = wb * a, wbv = wb * b;
            m0 += wa * Wb[0] + wbv * Wb[4];
            m1 += wa * Wb[1] + wbv * Wb[5];
            m2 += wa * Wb[2] + wbv * Wb[6];
            m3 += wa * Wb[3] + wbv * Wb[7];
        }
    }
    m0 += __shfl_xor(m0, 1, 64);
    m1 += __shfl_xor(m1, 1, 64);
    m2 += __shfl_xor(m2, 1, 64);
    m3 += __shfl_xor(m3, 1, 64);
    float deg = (float)(end - st);
    float cm = deg > 1.f ? deg : 1.f;
    float v0 = m0 / cm, v1 = m1 / cm, v2 = m2 / cm, v3 = m3 / cm;
    if (half == 0) {
        float4 o; o.x = v0; o.y = v1; o.z = v2; o.w = v3;
        *(float4*)&h2[4 * n] = o;
    }
    float ts[4], tq[4];
    ts[0] = half ? 0.f : v0; tq[0] = half ? 0.f : v0 * v0;
    ts[1] = half ? 0.f : v1; tq[1] = half ? 0.f : v1 * v1;
    ts[2] = half ? 0.f : v2; tq[2] = half ? 0.f : v2 * v2;
    ts[3] = half ? 0.f : v3; tq[3] = half ? 0.f : v3 * v3;
#pragma unroll
    for (int o = 32; o > 0; o >>= 1) {
#pragma unroll
        for (int ch = 0; ch < 4; ch++) {
            ts[ch] += __shfl_down(ts[ch], o, 64);
            tq[ch] += __shfl_down(tq[ch], o, 64);
        }
    }
    if ((tid & 63) == 0) {
#pragma unroll
        for (int ch = 0; ch < 4; ch++) {
            atomicAdd(&accum[ch], ts[ch]);
            atomicAdd(&accum[4 + ch], tq[ch]);
        }
    }
}

// ---- pooling: BN2 normalize, grid cluster, ordered-uint atomicMax ----------
__device__ __forceinline__ unsigned enc_float(float v) {
    unsigned u = __float_as_uint(v);
    return (v >= 0.f) ? (u | 0x80000000u) : ~u;
}

__global__ void pool_kernel(const float* __restrict__ h2,
                            const float* __restrict__ pos,
                            const float* __restrict__ params, // scale2[4], shift2[4]
                            unsigned* __restrict__ pooled, int N) {
    __shared__ unsigned lmax[64];
    for (int i = threadIdx.x; i < 64; i += blockDim.x) lmax[i] = 0u;
    __syncthreads();
    float sc[4], sh[4];
#pragma unroll
    for (int c = 0; c < 4; c++) { sc[c] = params[c]; sh[c] = params[4 + c]; }
    int stride = gridDim.x * blockDim.x;
    for (int n = blockIdx.x * blockDim.x + threadIdx.x; n < N; n += stride) {
        float px = pos[2 * n + 0], py = pos[2 * n + 1];
        int cx = (int)floorf(px * (1.f / 25.f));
        int cy = (int)floorf(py * (1.f / 25.f));
        cx = min(max(cx, 0), 3);
        cy = min(max(cy, 0), 3);
        int cl = cx + 4 * cy;
        float4 h = *(const float4*)&h2[4 * n];
        atomicMax(&lmax[4 * cl + 0], enc_float(h.x * sc[0] + sh[0]));
        atomicMax(&lmax[4 * cl + 1], enc_float(h.y * sc[1] + sh[1]));
        atomicMax(&lmax[4 * cl + 2], enc_float(h.z * sc[2] + sh[2]));
        atomicMax(&lmax[4 * cl + 3], enc_float(h.w * sc[3] + sh[3]));
    }
    __syncthreads();
    for (int i = threadIdx.x; i < 64; i += blockDim.x)
        if (lmax[i]) atomicMax(&pooled[i], lmax[i]);
}

// ---- final: decode pooled, FC 64->4 ----------------------------------------
__global__ void final_kernel(const unsigned* __restrict__ pooled,
                             const float* __restrict__ fcw, // [4][64]
                             float* __restrict__ out) {
    __shared__ float p[64];
    int t = threadIdx.x;
    if (t < 64) {
        unsigned u = pooled[t];
        float v = 0.f;
        if (u != 0u) {
            unsigned bits = (u & 0x80000000u) ? (u ^ 0x80000000u) : ~u;
            v = __uint_as_float(bits);
        }
        p[t] = v;
    }
    __syncthreads();
    if (t < 4) {
        float s = 0.f;
        for (int k = 0; k < 64; k++) s += p[k] * fcw[t * 64 + k];
        out[t] = s;
    }
}

// ---------------------------------------------------------------------------
extern "C" void kernel_launch(void* const* d_in, const int* in_sizes, int n_in,
                              void* d_out, int out_size, void* d_ws, size_t ws_size,
                              hipStream_t stream) {
    const float* x      = (const float*)d_in[0];
    const int*   ei     = (const int*)d_in[1];
    const float* attr   = (const float*)d_in[2];
    const float* pos    = (const float*)d_in[3];
    const float* W1     = (const float*)d_in[4];
    const float* W2     = (const float*)d_in[5];
    const float* gamma1 = (const float*)d_in[6];
    const float* beta1  = (const float*)d_in[7];
    const float* gamma2 = (const float*)d_in[8];
    const float* beta2  = (const float*)d_in[9];
    const float* fcw    = (const float*)d_in[10];
    float* out = (float*)d_out;

    const int N = in_sizes[0];       // 262144 = 2048*128
    const int E = in_sizes[2] / 3;   // 4194304

    // workspace layout
    uint4* part = (uint4*)d_ws;                          // E records (sorted in place)
    float* base = (float*)(part + E);
    float* accum  = base;                                // 12
    float* params = base + 12;                           // 12
    unsigned* pooled = (unsigned*)(base + 24);           // 64
    float* h1 = base + 88;                               // 2N
    float* h2 = h1 + 2 * (size_t)N;                      // 4N
    unsigned* cntArr  = (unsigned*)(h2 + 4 * (size_t)N); // NBUCK*BPART (scanned in place)
    unsigned* bktTot  = cntArr + (size_t)NBUCK * BPART;  // NBUCK
    unsigned* bktBase = bktTot + NBUCK;                  // NBUCK
    unsigned* nodeStart = bktBase + NBUCK;               // N+1

    hipMemsetAsync(base, 0, 88 * sizeof(float), stream);

    hist_kernel<<<BPART, TPB, 0, stream>>>(ei, E, cntArr);
    scan512_kernel<<<NBUCK, BPART, 0, stream>>>(cntArr, bktTot);
    scanbase_kernel<<<1, 512, 0, stream>>>(bktTot, bktBase, nodeStart, N, (unsigned)E);
    scatter_kernel<<<BPART, TPB, 0, stream>>>(ei, attr, bktBase, cntArr, part, E);
    sortagg1_kernel<<<NBUCK, TPB, 0, stream>>>(part, bktBase, bktTot, x, W1, h1, nodeStart, accum);
    bnparams_kernel<<<1, 64, 0, stream>>>(accum, gamma1, beta1, params, 2, 1.0f / (float)N);
    agg2_kernel<<<NBUCK, TPB, 0, stream>>>(part, nodeStart, h1, W2, params, h2, accum + 4);
    bnparams_kernel<<<1, 64, 0, stream>>>(accum + 4, gamma2, beta2, params + 4, 4, 1.0f / (float)N);
    pool_kernel<<<512, TPB, 0, stream>>>(h2, pos, params + 4, pooled, N);
    final_kernel<<<1, 64, 0, stream>>>(pooled, fcw, out);
}

// Round 5
// 901.831 us; speedup vs baseline: 1.7021x; 1.7021x over previous
//
#include <hip/hip_runtime.h>

// ---------------------------------------------------------------------------
// net_39041252721195: SplineConv(1->2) + ELU + BN + SplineConv(2->4) + BN
//                     + 4x4 grid max-pool + FC(64->4)
// K=2, DIM=3: pseudo in [0,1) => lo==0, idx==b. Basis weights = trilinear.
//
// Round 5: R2/R3 floor = per-edge LDS fp atomics (~10cyc/lane, serialized);
// R4 killer = ragged per-node reads (64 lines/wave-load, 4x over-fetch,
// latency-bound). Fix: node-sorted buckets consumed BLOCK-COALESCED with
// wave-segmented reduction (shfl_up inclusive scan keyed on node id);
// only run-boundary lanes (~4/64 records) touch LDS fp atomics. Sorted
// scatter goes straight to global (L2-resident 32KB/bucket) - no big LDS
// staging, no separate writeback; full occupancy.
// ---------------------------------------------------------------------------

#define TPB 256
#define NODES_PER_BUCK 128
#define BUCK_SHIFT 7
#define NBUCK 2048                  // N / 128 (N = 262144)
#define BPART 512                   // partition blocks
#define MAXR 10                     // records/thread in sortagg1 (cap 2560; mean 2048, sd 45)

__device__ __forceinline__ void basis_weights(float f0, float f1, float f2, float w[8]) {
    float g0 = 1.f - f0, g1 = 1.f - f1, g2 = 1.f - f2;
    w[0] = g0 * g1 * g2;  w[1] = f0 * g1 * g2;
    w[2] = g0 * f1 * g2;  w[3] = f0 * f1 * g2;
    w[4] = g0 * g1 * f2;  w[5] = f0 * g1 * f2;
    w[6] = g0 * f1 * f2;  w[7] = f0 * f1 * f2;
}

// ---- pass 1: per-block LDS histogram of dst>>7 -----------------------------
__global__ void hist_kernel(const int* __restrict__ ei, int E,
                            unsigned* __restrict__ cntArr /* [NBUCK][BPART] */) {
    __shared__ unsigned h[NBUCK];
    for (int i = threadIdx.x; i < NBUCK; i += TPB) h[i] = 0u;
    __syncthreads();
    int ch = (E + BPART - 1) / BPART;
    int s = blockIdx.x * ch;
    int e_end = min(E, s + ch);
    int e = s + threadIdx.x * 4;
    for (; e + 4 <= e_end; e += TPB * 4) {
        int4 d4 = *(const int4*)&ei[E + e];
        atomicAdd(&h[d4.x >> BUCK_SHIFT], 1u);
        atomicAdd(&h[d4.y >> BUCK_SHIFT], 1u);
        atomicAdd(&h[d4.z >> BUCK_SHIFT], 1u);
        atomicAdd(&h[d4.w >> BUCK_SHIFT], 1u);
    }
    for (e = e_end - (e_end - s) % (TPB * 4) + threadIdx.x; e < e_end; e += TPB)
        atomicAdd(&h[ei[E + e] >> BUCK_SHIFT], 1u);
    __syncthreads();
    for (int i = threadIdx.x; i < NBUCK; i += TPB)
        cntArr[i * BPART + blockIdx.x] = h[i];
}

// ---- scan: per-bucket exclusive prefix over BPART values, IN PLACE ---------
__global__ void scan512_kernel(unsigned* __restrict__ data,
                               unsigned* __restrict__ totals) {
    __shared__ unsigned s[BPART];
    int t = threadIdx.x, g = blockIdx.x;
    unsigned v = data[g * BPART + t];
    s[t] = v;
    __syncthreads();
    for (int o = 1; o < BPART; o <<= 1) {
        unsigned u = (t >= o) ? s[t - o] : 0u;
        __syncthreads();
        s[t] += u;
        __syncthreads();
    }
    data[g * BPART + t] = s[t] - v;     // exclusive
    if (t == BPART - 1) totals[g] = s[t];
}

// ---- scan of NBUCK bucket totals -> bucket bases; set nodeStart[N]=E -------
__global__ void scanbase_kernel(const unsigned* __restrict__ in,   // [NBUCK]
                                unsigned* __restrict__ excl,       // [NBUCK]
                                unsigned* __restrict__ nodeStart,
                                int N, unsigned Etot) {
    __shared__ unsigned s[512];
    int t = threadIdx.x;
    unsigned v0 = in[4 * t], v1 = in[4 * t + 1], v2 = in[4 * t + 2], v3 = in[4 * t + 3];
    unsigned sum = v0 + v1 + v2 + v3;
    s[t] = sum;
    __syncthreads();
    for (int o = 1; o < 512; o <<= 1) {
        unsigned u = (t >= o) ? s[t - o] : 0u;
        __syncthreads();
        s[t] += u;
        __syncthreads();
    }
    unsigned run = s[t] - sum;
    excl[4 * t] = run;          run += v0;
    excl[4 * t + 1] = run;      run += v1;
    excl[4 * t + 2] = run;      run += v2;
    excl[4 * t + 3] = run;
    if (t == 0) nodeStart[N] = Etot;
}

// ---- scatter edges into bucket-contiguous 16B records ----------------------
__global__ void scatter_kernel(const int* __restrict__ ei,
                               const float* __restrict__ attr,
                               const unsigned* __restrict__ bktBase,
                               const unsigned* __restrict__ preArr,
                               uint4* __restrict__ part, int E) {
    __shared__ unsigned cursor[NBUCK];
    for (int i = threadIdx.x; i < NBUCK; i += TPB)
        cursor[i] = bktBase[i] + preArr[i * BPART + blockIdx.x];
    __syncthreads();
    int ch = (E + BPART - 1) / BPART;
    int s = blockIdx.x * ch;
    int e_end = min(E, s + ch);
    int e = s + threadIdx.x * 4;
    for (; e + 4 <= e_end; e += TPB * 4) {
        int4 s4 = *(const int4*)&ei[e];
        int4 d4 = *(const int4*)&ei[E + e];
        float4 a0 = *(const float4*)&attr[3 * e];
        float4 a1 = *(const float4*)&attr[3 * e + 4];
        float4 a2 = *(const float4*)&attr[3 * e + 8];
        int srcs[4] = {s4.x, s4.y, s4.z, s4.w};
        int dsts[4] = {d4.x, d4.y, d4.z, d4.w};
        float f[4][3] = {{a0.x, a0.y, a0.z}, {a0.w, a1.x, a1.y},
                         {a1.z, a1.w, a2.x}, {a2.y, a2.z, a2.w}};
#pragma unroll
        for (int j = 0; j < 4; j++) {
            unsigned pos = atomicAdd(&cursor[dsts[j] >> BUCK_SHIFT], 1u);
            uint4 r;
            r.x = (unsigned)srcs[j] | ((unsigned)(dsts[j] & (NODES_PER_BUCK - 1)) << 18);
            r.y = __float_as_uint(f[j][0]);
            r.z = __float_as_uint(f[j][1]);
            r.w = __float_as_uint(f[j][2]);
            part[pos] = r;
        }
    }
    for (e = e_end - (e_end - s) % (TPB * 4) + threadIdx.x; e < e_end; e += TPB) {
        int src = ei[e], dst = ei[E + e];
        unsigned pos = atomicAdd(&cursor[dst >> BUCK_SHIFT], 1u);
        uint4 r;
        r.x = (unsigned)src | ((unsigned)(dst & (NODES_PER_BUCK - 1)) << 18);
        r.y = __float_as_uint(attr[3 * e]);
        r.z = __float_as_uint(attr[3 * e + 1]);
        r.w = __float_as_uint(attr[3 * e + 2]);
        part[pos] = r;
    }
}

// ---- sort bucket by node (global in-place) + layer-1 segmented agg ---------
__global__ void sortagg1_kernel(uint4* __restrict__ part,
                                const unsigned* __restrict__ bktBase,
                                const unsigned* __restrict__ bktTot,
                                const float* __restrict__ x,
                                const float* __restrict__ W1,
                                float* __restrict__ h1,
                                unsigned* __restrict__ nodeStart,
                                float* __restrict__ accum /* sum[2], sq[2] */) {
    __shared__ unsigned hist[NODES_PER_BUCK];
    __shared__ unsigned cursor[NODES_PER_BUCK];
    __shared__ float accA[NODES_PER_BUCK], accB[NODES_PER_BUCK];
    int tid = threadIdx.x;
    if (tid < NODES_PER_BUCK) {
        hist[tid] = 0u; accA[tid] = 0.f; accB[tid] = 0.f;
    }
    float w1[16];
#pragma unroll
    for (int i = 0; i < 16; i++) w1[i] = W1[i];
    __syncthreads();
    int g = blockIdx.x;
    unsigned s = bktBase[g], n_e = bktTot[g];
    uint4 rec[MAXR];
#pragma unroll
    for (int j = 0; j < MAXR; j++) {
        unsigned i = (unsigned)tid + j * 256u;
        if (i < n_e) {
            rec[j] = part[s + i];
            atomicAdd(&hist[rec[j].x >> 18], 1u);
        }
    }
    __syncthreads();
    unsigned myc = (tid < NODES_PER_BUCK) ? hist[tid] : 0u;   // degree, saved
    for (int o = 1; o < NODES_PER_BUCK; o <<= 1) {
        unsigned u = 0u;
        if (tid < NODES_PER_BUCK && tid >= o) u = hist[tid - o];
        __syncthreads();
        if (tid < NODES_PER_BUCK) hist[tid] += u;
        __syncthreads();
    }
    if (tid < NODES_PER_BUCK) {
        unsigned excl = hist[tid] - myc;
        cursor[tid] = excl;
        nodeStart[(g << BUCK_SHIFT) + tid] = s + excl;
    }
    __syncthreads();
    // scatter sorted records back to global (32KB region, L2-resident)
#pragma unroll
    for (int j = 0; j < MAXR; j++) {
        unsigned i = (unsigned)tid + j * 256u;
        if (i < n_e) {
            unsigned slot = atomicAdd(&cursor[rec[j].x >> 18], 1u);
            part[s + slot] = rec[j];
        }
    }
    __threadfence_block();
    __syncthreads();
    // coalesced re-read + wave-segmented reduction
    int lane = tid & 63;
    for (unsigned base0 = 0; base0 < n_e; base0 += 256u) {
        unsigned i = base0 + tid;
        int key = NODES_PER_BUCK - 1;   // invalid lanes merge into last run with 0
        float a0 = 0.f, a1 = 0.f;
        if (i < n_e) {
            uint4 r = part[s + i];
            key = r.x >> 18;
            float f0 = __uint_as_float(r.y), f1 = __uint_as_float(r.z), f2 = __uint_as_float(r.w);
            float w[8];
            basis_weights(f0, f1, f2, w);
            float wv0 = 0.f, wv1 = 0.f;
#pragma unroll
            for (int b = 0; b < 8; b++) {
                wv0 += w[b] * w1[2 * b];
                wv1 += w[b] * w1[2 * b + 1];
            }
            float xs = x[r.x & 0x3FFFF];
            a0 = xs * wv0;
            a1 = xs * wv1;
        }
#pragma unroll
        for (int o = 1; o < 64; o <<= 1) {
            int ku = __shfl_up(key, o, 64);
            float t0 = __shfl_up(a0, o, 64);
            float t1 = __shfl_up(a1, o, 64);
            if (lane >= o && ku == key) { a0 += t0; a1 += t1; }
        }
        int kn = __shfl_down(key, 1, 64);
        if (lane == 63 || kn != key) {
            atomicAdd(&accA[key], a0);
            atomicAdd(&accB[key], a1);
        }
    }
    __syncthreads();
    // finalize: mean + ELU + h1 write + BN1 stats
    float ts0 = 0.f, ts1 = 0.f, tq0 = 0.f, tq1 = 0.f;
    if (tid < NODES_PER_BUCK) {
        float cm = myc > 1u ? (float)myc : 1.f;
        float a = accA[tid] / cm, b = accB[tid] / cm;
        a = a > 0.f ? a : (__expf(a) - 1.f);
        b = b > 0.f ? b : (__expf(b) - 1.f);
        int n = (g << BUCK_SHIFT) + tid;
        h1[2 * n] = a; h1[2 * n + 1] = b;
        ts0 = a; tq0 = a * a;
        ts1 = b; tq1 = b * b;
    }
#pragma unroll
    for (int o = 32; o > 0; o >>= 1) {
        ts0 += __shfl_down(ts0, o, 64);
        ts1 += __shfl_down(ts1, o, 64);
        tq0 += __shfl_down(tq0, o, 64);
        tq1 += __shfl_down(tq1, o, 64);
    }
    if ((tid & 63) == 0 && tid < NODES_PER_BUCK) {
        atomicAdd(&accum[0], ts0);
        atomicAdd(&accum[1], ts1);
        atomicAdd(&accum[2], tq0);
        atomicAdd(&accum[3], tq1);
    }
}

// ---- BN params: scale = gamma*rsqrt(var+eps); shift = beta - mu*scale ------
__global__ void bnparams_kernel(const float* __restrict__ accum,
                                const float* __restrict__ gamma,
                                const float* __restrict__ beta,
                                float* __restrict__ params, int C, float invN) {
    int c = threadIdx.x;
    if (c < C) {
        float mu  = accum[c] * invN;
        float var = accum[C + c] * invN - mu * mu;
        float sc  = gamma[c] * rsqrtf(var + 1e-5f);
        params[c] = sc;
        params[C + c] = beta[c] - mu * sc;
    }
}

// ---- layer 2: coalesced stream over sorted bucket + segmented reduction ----
__global__ void agg2_kernel(const uint4* __restrict__ part,      // node-sorted
                            const unsigned* __restrict__ bktBase,
                            const unsigned* __restrict__ bktTot,
                            const unsigned* __restrict__ nodeStart,
                            const float* __restrict__ h1,
                            const float* __restrict__ W2,        // [8][2][4]
                            const float* __restrict__ params,    // sc1[2], sh1[2]
                            float* __restrict__ h2,
                            float* __restrict__ accum /* sum[4], sq[4] */) {
    __shared__ float ac0[NODES_PER_BUCK], ac1[NODES_PER_BUCK],
                     ac2[NODES_PER_BUCK], ac3[NODES_PER_BUCK];
    int tid = threadIdx.x;
    if (tid < NODES_PER_BUCK) {
        ac0[tid] = 0.f; ac1[tid] = 0.f; ac2[tid] = 0.f; ac3[tid] = 0.f;
    }
    float w2[64];
#pragma unroll
    for (int i = 0; i < 64; i++) w2[i] = W2[i];
    float sc0 = params[0], sc1 = params[1], sh0 = params[2], sh1 = params[3];
    __syncthreads();
    int g = blockIdx.x;
    unsigned s = bktBase[g], n_e = bktTot[g];
    int lane = tid & 63;
    for (unsigned base0 = 0; base0 < n_e; base0 += 256u) {
        unsigned i = base0 + tid;
        int key = NODES_PER_BUCK - 1;
        float m0 = 0.f, m1 = 0.f, m2 = 0.f, m3 = 0.f;
        if (i < n_e) {
            uint4 r = part[s + i];
            key = r.x >> 18;
            float f0 = __uint_as_float(r.y), f1 = __uint_as_float(r.z), f2 = __uint_as_float(r.w);
            float w[8];
            basis_weights(f0, f1, f2, w);
            float2 hv = *(const float2*)&h1[2 * (r.x & 0x3FFFF)];
            float a = hv.x * sc0 + sh0;
            float b = hv.y * sc1 + sh1;
#pragma unroll
            for (int bb = 0; bb < 8; bb++) {
                float wb = w[bb];
                const float* Wb = &w2[8 * bb];
                float wa = wb * a, wbv = wb * b;
                m0 += wa * Wb[0] + wbv * Wb[4];
                m1 += wa * Wb[1] + wbv * Wb[5];
                m2 += wa * Wb[2] + wbv * Wb[6];
                m3 += wa * Wb[3] + wbv * Wb[7];
            }
        }
#pragma unroll
        for (int o = 1; o < 64; o <<= 1) {
            int ku = __shfl_up(key, o, 64);
            float t0 = __shfl_up(m0, o, 64);
            float t1 = __shfl_up(m1, o, 64);
            float t2 = __shfl_up(m2, o, 64);
            float t3 = __shfl_up(m3, o, 64);
            if (lane >= o && ku == key) { m0 += t0; m1 += t1; m2 += t2; m3 += t3; }
        }
        int kn = __shfl_down(key, 1, 64);
        if (lane == 63 || kn != key) {
            atomicAdd(&ac0[key], m0);
            atomicAdd(&ac1[key], m1);
            atomicAdd(&ac2[key], m2);
            atomicAdd(&ac3[key], m3);
        }
    }
    __syncthreads();
    float ts[4] = {0.f, 0.f, 0.f, 0.f}, tq[4] = {0.f, 0.f, 0.f, 0.f};
    if (tid < NODES_PER_BUCK) {
        int n = (g << BUCK_SHIFT) + tid;
        unsigned deg = nodeStart[n + 1] - nodeStart[n];
        float cm = deg > 1u ? (float)deg : 1.f;
        float v0 = ac0[tid] / cm, v1 = ac1[tid] / cm, v2 = ac2[tid] / cm, v3 = ac3[tid] / cm;
        float4 o4; o4.x = v0; o4.y = v1; o4.z = v2; o4.w = v3;
        *(float4*)&h2[4 * n] = o4;
        ts[0] = v0; tq[0] = v0 * v0;
        ts[1] = v1; tq[1] = v1 * v1;
        ts[2] = v2; tq[2] = v2 * v2;
        ts[3] = v3; tq[3] = v3 * v3;
    }
#pragma unroll
    for (int o = 32; o > 0; o >>= 1) {
#pragma unroll
        for (int ch = 0; ch < 4; ch++) {
            ts[ch] += __shfl_down(ts[ch], o, 64);
            tq[ch] += __shfl_down(tq[ch], o, 64);
        }
    }
    if ((tid & 63) == 0 && tid < NODES_PER_BUCK) {
#pragma unroll
        for (int ch = 0; ch < 4; ch++) {
            atomicAdd(&accum[ch], ts[ch]);
            atomicAdd(&accum[4 + ch], tq[ch]);
        }
    }
}

// ---- pooling: BN2 normalize, grid cluster, ordered-uint atomicMax ----------
__device__ __forceinline__ unsigned enc_float(float v) {
    unsigned u = __float_as_uint(v);
    return (v >= 0.f) ? (u | 0x80000000u) : ~u;
}

__global__ void pool_kernel(const float* __restrict__ h2,
                            const float* __restrict__ pos,
                            const float* __restrict__ params, // scale2[4], shift2[4]
                            unsigned* __restrict__ pooled, int N) {
    __shared__ unsigned lmax[64];
    for (int i = threadIdx.x; i < 64; i += blockDim.x) lmax[i] = 0u;
    __syncthreads();
    float sc[4], sh[4];
#pragma unroll
    for (int c = 0; c < 4; c++) { sc[c] = params[c]; sh[c] = params[4 + c]; }
    int stride = gridDim.x * blockDim.x;
    for (int n = blockIdx.x * blockDim.x + threadIdx.x; n < N; n += stride) {
        float px = pos[2 * n + 0], py = pos[2 * n + 1];
        int cx = (int)floorf(px * (1.f / 25.f));
        int cy = (int)floorf(py * (1.f / 25.f));
        cx = min(max(cx, 0), 3);
        cy = min(max(cy, 0), 3);
        int cl = cx + 4 * cy;
        float4 h = *(const float4*)&h2[4 * n];
        atomicMax(&lmax[4 * cl + 0], enc_float(h.x * sc[0] + sh[0]));
        atomicMax(&lmax[4 * cl + 1], enc_float(h.y * sc[1] + sh[1]));
        atomicMax(&lmax[4 * cl + 2], enc_float(h.z * sc[2] + sh[2]));
        atomicMax(&lmax[4 * cl + 3], enc_float(h.w * sc[3] + sh[3]));
    }
    __syncthreads();
    for (int i = threadIdx.x; i < 64; i += blockDim.x)
        if (lmax[i]) atomicMax(&pooled[i], lmax[i]);
}

// ---- final: decode pooled, FC 64->4 ----------------------------------------
__global__ void final_kernel(const unsigned* __restrict__ pooled,
                             const float* __restrict__ fcw, // [4][64]
                             float* __restrict__ out) {
    __shared__ float p[64];
    int t = threadIdx.x;
    if (t < 64) {
        unsigned u = pooled[t];
        float v = 0.f;
        if (u != 0u) {
            unsigned bits = (u & 0x80000000u) ? (u ^ 0x80000000u) : ~u;
            v = __uint_as_float(bits);
        }
        p[t] = v;
    }
    __syncthreads();
    if (t < 4) {
        float s = 0.f;
        for (int k = 0; k < 64; k++) s += p[k] * fcw[t * 64 + k];
        out[t] = s;
    }
}

// ---------------------------------------------------------------------------
extern "C" void kernel_launch(void* const* d_in, const int* in_sizes, int n_in,
                              void* d_out, int out_size, void* d_ws, size_t ws_size,
                              hipStream_t stream) {
    const float* x      = (const float*)d_in[0];
    const int*   ei     = (const int*)d_in[1];
    const float* attr   = (const float*)d_in[2];
    const float* pos    = (const float*)d_in[3];
    const float* W1     = (const float*)d_in[4];
    const float* W2     = (const float*)d_in[5];
    const float* gamma1 = (const float*)d_in[6];
    const float* beta1  = (const float*)d_in[7];
    const float* gamma2 = (const float*)d_in[8];
    const float* beta2  = (const float*)d_in[9];
    const float* fcw    = (const float*)d_in[10];
    float* out = (float*)d_out;

    const int N = in_sizes[0];       // 262144 = 2048*128
    const int E = in_sizes[2] / 3;   // 4194304

    // workspace layout
    uint4* part = (uint4*)d_ws;                          // E records (sorted in place)
    float* base = (float*)(part + E);
    float* accum  = base;                                // 12
    float* params = base + 12;                           // 12
    unsigned* pooled = (unsigned*)(base + 24);           // 64
    float* h1 = base + 88;                               // 2N
    float* h2 = h1 + 2 * (size_t)N;                      // 4N
    unsigned* cntArr  = (unsigned*)(h2 + 4 * (size_t)N); // NBUCK*BPART (scanned in place)
    unsigned* bktTot  = cntArr + (size_t)NBUCK * BPART;  // NBUCK
    unsigned* bktBase = bktTot + NBUCK;                  // NBUCK
    unsigned* nodeStart = bktBase + NBUCK;               // N+1

    hipMemsetAsync(base, 0, 88 * sizeof(float), stream);

    hist_kernel<<<BPART, TPB, 0, stream>>>(ei, E, cntArr);
    scan512_kernel<<<NBUCK, BPART, 0, stream>>>(cntArr, bktTot);
    scanbase_kernel<<<1, 512, 0, stream>>>(bktTot, bktBase, nodeStart, N, (unsigned)E);
    scatter_kernel<<<BPART, TPB, 0, stream>>>(ei, attr, bktBase, cntArr, part, E);
    sortagg1_kernel<<<NBUCK, TPB, 0, stream>>>(part, bktBase, bktTot, x, W1, h1, nodeStart, accum);
    bnparams_kernel<<<1, 64, 0, stream>>>(accum, gamma1, beta1, params, 2, 1.0f / (float)N);
    agg2_kernel<<<NBUCK, TPB, 0, stream>>>(part, bktBase, bktTot, nodeStart, h1, W2, params, h2, accum + 4);
    bnparams_kernel<<<1, 64, 0, stream>>>(accum + 4, gamma2, beta2, params + 4, 4, 1.0f / (float)N);
    pool_kernel<<<512, TPB, 0, stream>>>(h2, pos, params + 4, pooled, N);
    final_kernel<<<1, 64, 0, stream>>>(pooled, fcw, out);
}